// Round 17
// baseline (98.721 us; speedup 1.0000x reference)
//
#include <hip/hip_runtime.h>

#define T_STEPS 512
#define G_CELLS 4096
#define L_UHN   15
#define GRP     16
#define NGRP    (T_STEPS / GRP)   // 32
#define NITER   (NGRP + 2)        // 34: snow@k, vad@k-1, route@k-2
#define CPB     64                // cells per block (one lane each)
#define NZF     1e-5f
#define LOG2E   1.44269504088896340736f
#define LOG2_10 3.32192809488736234787f

__device__ __forceinline__ float fexp2(float x) { return __builtin_amdgcn_exp2f(x); }
__device__ __forceinline__ float flog2(float x) { return __builtin_amdgcn_logf(x); }
__device__ __forceinline__ float fmed3(float x, float lo, float hi) { return __builtin_amdgcn_fmed3f(x, lo, hi); }
__device__ __forceinline__ float fpow(float a, float b) { return fexp2(b * flog2(a)); }
__device__ __forceinline__ float fexp(float x) { return fexp2(x * LOG2E); }
__device__ __forceinline__ float fsigmoid(float v) { return 1.0f / (1.0f + fexp(-v)); }
__device__ __forceinline__ float fdescale(float s, float lo, float hi) { return lo + s * (hi - lo); }

// Branch-free poly exp2. The 2^n scale is built with int ops IN PARALLEL with the
// Horner chain (no ldexpf!): chain = rint+sub+6fma+mul ~= 48 cy. Valid for
// n in [-126,127]; our args are in [-54, 8]. Taylor ln2^k/k!, rel err ~1.2e-7.
__device__ __forceinline__ float pexp2(float x) {
    float n = rintf(x);                                  // v_rndne_f32
    float r = x - n;                                     // r in [-0.5, 0.5]
    float s = __int_as_float(((int)n + 127) << 23);      // 2^n  (off the r-chain)
    float p = fmaf(r, 1.54035060e-4f, 1.33335581e-3f);
    p = fmaf(r, p, 9.61812911e-3f);
    p = fmaf(r, p, 5.55041087e-2f);
    p = fmaf(r, p, 2.40226507e-1f);
    p = fmaf(r, p, 6.93147181e-1f);
    p = fmaf(r, p, 1.0f);
    return p * s;
}

__device__ __forceinline__ void block_barrier() {
    asm volatile("s_waitcnt lgkmcnt(0)" ::: "memory");
    __builtin_amdgcn_s_barrier();
}

// Pipeline (one barrier per iteration k, k = 0..NITER-1):
//   snow02 / hmets : group k    -> ob[k&1]
//   vad            : group k-1  (reads ob[(k-1)&1] directly) -> pr[(k-1)&1]
//   phr+route      : group k-2  (reads pr[(k-2)&1] directly) -> out

// ===================== wave 0: hbv + simple (combined slot) =====================
__device__ __forceinline__ void snow02_wave(const float* __restrict__ x,
                                            const float* __restrict__ pp,
                                            float (*ob)[2][GRP][CPB],
                                            int lane, int g)
{
    const float ddf_min  = fdescale(fsigmoid(pp[0]), 0.0f, 20.0f);
    const float ddf_plus = fdescale(fsigmoid(pp[1]), 0.0f, 20.0f);
    const float Kcum     = fdescale(fsigmoid(pp[2]), 0.01f, 0.2f);
    const float Kf       = fdescale(fsigmoid(pp[3]), 0.0f, 5.0f);
    const float Tbf      = fdescale(fsigmoid(pp[5]), -5.0f, 2.0f);
    const float SWI      = fdescale(fsigmoid(pp[7]), 0.0f, 0.4f);
    const float Tbm      = fdescale(fsigmoid(pp[8]), -2.0f, 3.0f);
    const float ddfsum   = ddf_min + ddf_plus;
    const float ddfK     = ddf_min * Kcum;

    float w0, w2_;
    {
        float r0 = pp[24], r1 = pp[25], r2 = pp[26];
        float m = fmaxf(fmaxf(r0, r1), r2);
        float e0 = fexp(r0 - m), e1 = fexp(r1 - m), e2 = fexp(r2 - m);
        float inv = 1.0f / (e0 + e1 + e2);
        w0 = e0 * inv; w2_ = e2 * inv;
    }

    float sp0 = 0.f, lw0 = 0.f, cm0 = 0.f;   // hbv
    float sp2 = 0.f, cm2 = 0.f;              // simple

    float bR[GRP], bS[GRP], bD[GRP], bX[GRP];
    float rawP[GRP], rawT[GRP];
    #pragma unroll
    for (int j = 0; j < GRP; ++j) {
        size_t a = ((size_t)j * G_CELLS + (size_t)g) * 3;
        rawP[j] = x[a]; rawT[j] = x[a + 1];
    }
    #pragma unroll
    for (int j = 0; j < GRP; ++j) {
        float tm = rawT[j], prcp = rawP[j];
        bR[j] = (tm > 0.0f) ? prcp : 0.0f;
        bS[j] = prcp - bR[j];
        bD[j] = tm - Tbm;
        bX[j] = Kf * fmaxf(Tbf - tm, NZF);
    }

    for (int k = 0; k < NITER; ++k) {
        block_barrier();
        if (k < NGRP) {
            const int kn = (k + 1 < NGRP) ? k + 1 : NGRP - 1;
            #pragma unroll
            for (int j = 0; j < GRP; ++j) {
                size_t a = ((size_t)(kn * GRP + j) * G_CELLS + (size_t)g) * 3;
                rawP[j] = x[a]; rawT[j] = x[a + 1];
            }

            const int b = k & 1;
            #pragma unroll
            for (int j = 0; j < GRP; ++j) {
                const float rain = bR[j], snow = bS[j], dtm = bD[j];
                float oA, oB;
                {   // hbv
                    float ddf  = fminf(ddfsum, fmaf(ddfK, cm0, ddf_min));
                    float pm   = fmaxf(ddf * dtm, 0.0f);
                    float rfz  = fminf(bX[j], lw0);
                    sp0 = sp0 + snow + rfz;
                    float melt = fminf(pm, sp0 + snow + rfz);   // reference quirk
                    cm0 = (sp0 > NZF) ? (cm0 + melt) : 0.0f;
                    sp0 = fmaxf(sp0 - melt, NZF);
                    float wret = SWI * sp0;
                    float wtmp = lw0 + melt + rain;
                    oA = fmaxf(wtmp - wret, 0.0f);
                    lw0 = fminf(wtmp, wret);
                }
                {   // simple
                    float ddf  = fminf(ddfsum, fmaf(ddfK, cm2, ddf_min));
                    float pm   = fmaxf(ddf * dtm, 0.0f);
                    float melt = fminf(pm, sp2);
                    sp2 = sp2 + snow - melt;
                    oB = melt + rain;
                    cm2 = (sp2 > NZF) ? (cm2 + melt) : 0.0f;
                }
                ob[b][0][j][lane] = w0 * oA + w2_ * oB;
            }

            #pragma unroll
            for (int j = 0; j < GRP; ++j) {
                float tm = rawT[j], prcp = rawP[j];
                bR[j] = (tm > 0.0f) ? prcp : 0.0f;
                bS[j] = prcp - bR[j];
                bD[j] = tm - Tbm;
                bX[j] = Kf * fmaxf(Tbf - tm, NZF);
            }
        }
    }
}

// ===================== wave 1: hmets =====================
__device__ __forceinline__ void snow1_wave(const float* __restrict__ x,
                                           const float* __restrict__ pp,
                                           float (*ob)[2][GRP][CPB],
                                           int lane, int g)
{
    const float ddf_min  = fdescale(fsigmoid(pp[0]), 0.0f, 20.0f);
    const float ddf_plus = fdescale(fsigmoid(pp[1]), 0.0f, 20.0f);
    const float Kcum     = fdescale(fsigmoid(pp[2]), 0.01f, 0.2f);
    const float Kf       = fdescale(fsigmoid(pp[3]), 0.0f, 5.0f);
    const float exp_fe   = fdescale(fsigmoid(pp[4]), 0.0f, 1.0f);
    const float Tbf      = fdescale(fsigmoid(pp[5]), -5.0f, 2.0f);
    const float Ccum     = fdescale(fsigmoid(pp[6]), 0.005f, 0.05f);
    const float Tbm      = fdescale(fsigmoid(pp[8]), -2.0f, 3.0f);
    const float fcmin    = fdescale(fsigmoid(pp[9]), 0.0f, 0.1f);
    const float fcsum    = fcmin + fdescale(fsigmoid(pp[10]), 0.01f, 0.25f);
    const float ddfsum   = ddf_min + ddf_plus;
    const float ddfK     = ddf_min * Kcum;

    float w1;
    {
        float r0 = pp[24], r1 = pp[25], r2 = pp[26];
        float m = fmaxf(fmaxf(r0, r1), r2);
        float e0 = fexp(r0 - m), e1 = fexp(r1 - m), e2 = fexp(r2 - m);
        w1 = e1 / (e0 + e1 + e2);
    }

    float sp = 0.f, lw = 0.f, cm = 0.f;

    float bR[GRP], bS[GRP], bD[GRP], bX[GRP];
    float rawP[GRP], rawT[GRP];
    #pragma unroll
    for (int j = 0; j < GRP; ++j) {
        size_t a = ((size_t)j * G_CELLS + (size_t)g) * 3;
        rawP[j] = x[a]; rawT[j] = x[a + 1];
    }
    #pragma unroll
    for (int j = 0; j < GRP; ++j) {
        float tm = rawT[j], prcp = rawP[j];
        bR[j] = (tm > 0.0f) ? prcp : 0.0f;
        bS[j] = prcp - bR[j];
        bD[j] = tm - Tbm;
        bX[j] = Kf * fpow(fmaxf(Tbf - tm, NZF), exp_fe);
    }

    for (int k = 0; k < NITER; ++k) {
        block_barrier();
        if (k < NGRP) {
            const int kn = (k + 1 < NGRP) ? k + 1 : NGRP - 1;
            #pragma unroll
            for (int j = 0; j < GRP; ++j) {
                size_t a = ((size_t)(kn * GRP + j) * G_CELLS + (size_t)g) * 3;
                rawP[j] = x[a]; rawT[j] = x[a + 1];
            }

            const int b = k & 1;
            #pragma unroll
            for (int j = 0; j < GRP; ++j) {
                const float rain = bR[j], snow = bS[j], dtm = bD[j];
                float ddf  = fminf(ddfsum, fmaf(ddfK, cm, ddf_min));
                float pm   = fmaxf(ddf * dtm, 0.0f);
                float rfz  = fminf(bX[j], lw);
                lw -= rfz; sp += rfz;
                float melt = fminf(pm, sp + snow);
                sp = sp + snow - melt;
                cm = (sp > NZF) ? (cm + melt) : 0.0f;
                float wrf  = fmaxf(fcsum * (1.0f - Ccum * cm), fcmin);
                float wret = wrf * sp;
                float wtmp = lw + melt + rain;
                float o    = fmaxf(wtmp - wret, 0.0f);
                lw = fminf(wtmp, wret);
                cm = (sp > NZF) ? (cm + melt) : 0.0f;      // reference quirk: double update
                ob[b][1][j][lane] = w1 * o;
            }

            #pragma unroll
            for (int j = 0; j < GRP; ++j) {
                float tm = rawT[j], prcp = rawP[j];
                bR[j] = (tm > 0.0f) ? prcp : 0.0f;
                bS[j] = prcp - bR[j];
                bD[j] = tm - Tbm;
                bX[j] = Kf * fpow(fmaxf(Tbf - tm, NZF), exp_fe);
            }
        }
    }
}

// ===================== wave 2: vadose chain (lag 1, poly-exp2 with parallel scale) =====================
__device__ __forceinline__ void vad_wave(const float* __restrict__ x,
                                         const float* __restrict__ pp,
                                         float (*ob)[2][GRP][CPB],
                                         float (*pr)[2][GRP][CPB],
                                         int lane, int g)
{
    const float vmax        = fdescale(fsigmoid(pp[11]), 0.001f, 500.0f);
    const float hmets_alpha = fdescale(fsigmoid(pp[12]), 0.0f, 1.0f);
    const float vic_beta    = fdescale(fsigmoid(pp[13]), 0.1f, 3.0f);
    const float hbv_beta    = fdescale(fsigmoid(pp[14]), 0.5f, 3.0f);
    const float quickflow_k = fdescale(fsigmoid(pp[15]), -5.0f, -2.0f);
    const float qn          = fdescale(fsigmoid(pp[16]), 0.5f, 2.0f);
    const float mmax        = fdescale(fsigmoid(pp[17]), 0.0f, 100.0f);
    const float lamb        = fdescale(fsigmoid(pp[18]), 5.0f, 10.0f);
    const float ET_eff      = fdescale(fsigmoid(pp[21]), 0.0f, 3.0f);
    const float cv2p        = fdescale(fsigmoid(pp[22]), 1e-5f, 0.02f);

    float w4, w5, w6, w7, w8, w9;
    {
        float r0 = pp[27], r1 = pp[28], r2 = pp[29];
        float m = fmaxf(fmaxf(r0, r1), r2);
        float e0 = fexp(r0 - m), e1 = fexp(r1 - m), e2 = fexp(r2 - m);
        float inv = 1.0f / (e0 + e1 + e2);
        w4 = e0 * inv; w5 = e1 * inv; w6 = e2 * inv;
    }
    {
        float r0 = pp[30], r1 = pp[31], r2 = pp[32];
        float m = fmaxf(fmaxf(r0, r1), r2);
        float e0 = fexp(r0 - m), e1 = fexp(r1 - m), e2 = fexp(r2 - m);
        float inv = 1.0f / (e0 + e1 + e2);
        w7 = e0 * inv; w8 = e1 * inv; w9 = e2 * inv;
    }

    const float inv_vmax    = 1.0f / vmax;
    const float qk10        = fexp2(quickflow_k * LOG2_10);
    const float qf_top_coef = mmax * (vmax / qn) * fexp2(-qn * flog2(lamb));
    const float w7qk        = w7 * qk10;
    const float hi_clamp    = 1.0f - NZF;
    const float l2top       = flog2(qf_top_coef);
    const float l2vic       = flog2(mmax);
    const float one_m_cv2p  = 1.0f - cv2p;
    const float k_vv        = one_m_cv2p * inv_vmax;

    float vad = 0.f;
    float VV  = 0.f;     // == vad * inv_vmax

    float petReg[GRP], petNew[GRP];
    #pragma unroll
    for (int j = 0; j < GRP; ++j)
        petReg[j] = x[((size_t)j * G_CELLS + (size_t)g) * 3 + 2];

    for (int k = 0; k < NITER; ++k) {
        block_barrier();
        if (k >= 1 && k <= NGRP) {
            const int kg = k - 1;
            const int kn = (kg + 1 < NGRP) ? kg + 1 : NGRP - 1;
            #pragma unroll
            for (int j = 0; j < GRP; ++j)
                petNew[j] = x[((size_t)(kn * GRP + j) * G_CELLS + (size_t)g) * 3 + 2];

            const int bo   = kg & 1;
            const int slot = kg & 1;
            #pragma unroll
            for (int j = 0; j < GRP; ++j) {
                const float rrj = ob[bo][0][j][lane] + ob[bo][1][j][lane];
                const float pej = petReg[j] * ET_eff;
                float om  = fmed3(1.0f - VV, NZF, hi_clamp);
                float l1  = flog2(om);
                float phbv = pexp2(hbv_beta * l1);
                float pvic = pexp2(vic_beta * l1);
                float a4 = w4 * rrj;
                float a6 = w6 * rrj;
                float base = fmaf(w5 * rrj, fmaf(-hmets_alpha, VV, 1.0f), a6);
                float inf = fmaf(a4, phbv, fmaf(-a6, pvic, base));
                inf = fmed3(inf, 0.0f, rrj);
                float surface = rrj - inf;
                float vad1 = vad + inf;
                float VV1  = fmaf(inf, inv_vmax, VV);
                float sprop1 = fmed3(VV1, NZF, hi_clamp);
                float lq = flog2(sprop1);
                float topt = pexp2(fmaf(qn, lq, l2top));
                float vict = pexp2(fmaf(qn, lq, l2vic));
                float vad2 = fmaxf(fmaf(-pej, sprop1, vad1), 0.0f);
                float qf_top = fminf(topt, vad2);
                float qf_vic = fminf(vict, vad2);
                float S  = fmaf(w7qk, vad2, fmaf(w8, qf_top, w9 * qf_vic));
                float qf = fminf(S, vad2);
                float vad3 = vad2 - qf;

                pr[slot][0][j][lane] = cv2p * vad3;
                pr[slot][1][j][lane] = surface + qf;
                vad = vad3 * one_m_cv2p;
                VV  = vad3 * k_vv;
            }

            #pragma unroll
            for (int j = 0; j < GRP; ++j) petReg[j] = petNew[j];
        }
    }
}

// ===================== wave 3: phreatic chain + fused routing (lag 2) =====================
__device__ __forceinline__ void phr_route_wave(const float* __restrict__ pp,
                                               float (*pr)[2][GRP][CPB],
                                               float* __restrict__ out,
                                               int lane, int g)
{
    const float baseflow_k = fdescale(fsigmoid(pp[19]), -5.0f, -1.0f);
    const float bn         = fdescale(fsigmoid(pp[20]), 0.5f, 2.0f);
    float w10, w11;
    {
        float r0 = pp[33], r1 = pp[34];
        float m = fmaxf(r0, r1);
        float e0 = fexp(r0 - m), e1 = fexp(r1 - m);
        float inv = 1.0f / (e0 + e1);
        w10 = e0 * inv; w11 = e1 * inv;
    }
    const float bk10 = fexp2(baseflow_k * LOG2_10);
    const float c_b1 = w10 * bk10, c_b2 = w11 * bk10;

    const float a1 = fdescale(fsigmoid(pp[35]), 0.3f, 20.0f);
    const float b1 = fdescale(fsigmoid(pp[36]), 0.01f, 5.0f);
    const float a2 = fdescale(fsigmoid(pp[37]), 0.5f, 13.0f);
    const float b2 = fdescale(fsigmoid(pp[38]), 0.15f, 1.5f);

    const float LOG2T[L_UHN] = {
        -1.0f, 0.58496250072116f, 1.32192809488736f, 1.80735492205760f,
        2.16992500144231f, 2.45943161863730f, 2.70043971814109f,
        2.90689059560852f, 3.08746284125034f, 3.24792751344359f,
        3.39231742277876f, 3.52356195605701f, 3.64385618977472f,
        3.75488750216347f, 3.85798099512757f };

    float uh1[L_UHN], uh2[L_UHN];
    {
        float rb1 = LOG2E / b1, rb2 = LOG2E / b2;
        float s1 = 0.0f, s2 = 0.0f;
        #pragma unroll
        for (int kk = 0; kk < L_UHN; ++kk) {
            float tk = (float)kk + 0.5f;
            float v1 = fexp2((a1 - 1.0f) * LOG2T[kk] - tk * rb1);
            float v2 = fexp2((a2 - 1.0f) * LOG2T[kk] - tk * rb2);
            uh1[kk] = v1; uh2[kk] = v2; s1 += v1; s2 += v2;
        }
        float i1 = 1.0f / s1, i2 = 1.0f / s2;
        #pragma unroll
        for (int kk = 0; kk < L_UHN; ++kk) { uh1[kk] *= i1; uh2[kk] *= i2; }
    }

    float phr = 0.f;
    float fut[L_UHN];
    #pragma unroll
    for (int kk = 0; kk < L_UHN; ++kk) fut[kk] = 0.0f;

    for (int k = 0; k < NITER; ++k) {
        block_barrier();
        if (k >= 2) {
            const int kg = k - 2;
            const int slot = kg & 1;
            #pragma unroll
            for (int j = 0; j < GRP; ++j) {
                float pc = pr[slot][0][j][lane];
                float qt = pr[slot][1][j][lane];
                phr += pc;
                float pb = fexp2(bn * flog2(fmaxf(phr, NZF)));
                float bf = fminf(fmaf(c_b1, phr, c_b2 * pb), phr);
                phr -= bf;

                #pragma unroll
                for (int kk = 0; kk < L_UHN; ++kk)
                    fut[kk] = fmaf(uh1[kk], qt, fmaf(uh2[kk], bf, fut[kk]));
                out[(size_t)(kg * GRP + j) * G_CELLS + (size_t)g] = fut[0];
                #pragma unroll
                for (int kk = 0; kk < L_UHN - 1; ++kk) fut[kk] = fut[kk + 1];
                fut[L_UHN - 1] = 0.0f;
            }
        }
    }
}

__global__ __launch_bounds__(256, 1) void pipeline_kernel(
    const float* __restrict__ x, const float* __restrict__ params,
    float* __restrict__ out)
{
    __shared__ float ob[2][2][GRP][CPB];    // 16 KB  [buf][0=hbv+simple,1=hmets]
    __shared__ float pr[2][2][GRP][CPB];    // 16 KB  [slot][0=perc,1=quick]
    const int lane = threadIdx.x & 63;
    const int wave = threadIdx.x >> 6;
    const int g    = blockIdx.x * CPB + lane;
    const float* pp = params + ((size_t)(T_STEPS - 1) * G_CELLS + (size_t)g) * 39;

    if (wave == 0)      snow02_wave(x, pp, ob, lane, g);
    else if (wave == 1) snow1_wave(x, pp, ob, lane, g);
    else if (wave == 2) vad_wave(x, pp, ob, pr, lane, g);
    else                phr_route_wave(pp, pr, out, lane, g);
}

extern "C" void kernel_launch(void* const* d_in, const int* in_sizes, int n_in,
                              void* d_out, int out_size, void* d_ws, size_t ws_size,
                              hipStream_t stream) {
    const float* x      = (const float*)d_in[0];
    const float* params = (const float*)d_in[1];
    float* out          = (float*)d_out;
    pipeline_kernel<<<dim3(G_CELLS / CPB), dim3(256), 0, stream>>>(x, params, out);
}

// Round 18
// 71.365 us; speedup vs baseline: 1.3833x; 1.3833x over previous
//
#include <hip/hip_runtime.h>

#define T_STEPS 512
#define G_CELLS 4096
#define L_UHN   15
#define GRP     32
#define NGRP    (T_STEPS / GRP)   // 16
#define NITER   (NGRP + 2)        // 18: snow@k, vad@k-1, route@k-2
#define CPB     64                // cells per block (one lane each)
#define NZF     1e-5f
#define LOG2E   1.44269504088896340736f
#define LOG2_10 3.32192809488736234787f

__device__ __forceinline__ float fexp2(float x) { return __builtin_amdgcn_exp2f(x); }
__device__ __forceinline__ float flog2(float x) { return __builtin_amdgcn_logf(x); }
__device__ __forceinline__ float fmed3(float x, float lo, float hi) { return __builtin_amdgcn_fmed3f(x, lo, hi); }
__device__ __forceinline__ float fpow(float a, float b) { return fexp2(b * flog2(a)); }
__device__ __forceinline__ float fexp(float x) { return fexp2(x * LOG2E); }
__device__ __forceinline__ float fsigmoid(float v) { return 1.0f / (1.0f + fexp(-v)); }
__device__ __forceinline__ float fdescale(float s, float lo, float hi) { return lo + s * (hi - lo); }

__device__ __forceinline__ void block_barrier() {
    asm volatile("s_waitcnt lgkmcnt(0)" ::: "memory");
    __builtin_amdgcn_s_barrier();
}

// Pipeline (one barrier per iteration k, k = 0..NITER-1):
//   snow02 / hmets : group k    -> ob[k&1]
//   vad            : group k-1  (reads ob[(k-1)&1] directly) -> pr[(k-1)&1]
//   phr+route      : group k-2  (reads pr[(k-2)&1] directly) -> out

// ===================== wave 0: hbv + simple (combined slot) =====================
__device__ __forceinline__ void snow02_wave(const float* __restrict__ x,
                                            const float* __restrict__ pp,
                                            float (*ob)[2][GRP][CPB],
                                            int lane, int g)
{
    const float ddf_min  = fdescale(fsigmoid(pp[0]), 0.0f, 20.0f);
    const float ddf_plus = fdescale(fsigmoid(pp[1]), 0.0f, 20.0f);
    const float Kcum     = fdescale(fsigmoid(pp[2]), 0.01f, 0.2f);
    const float Kf       = fdescale(fsigmoid(pp[3]), 0.0f, 5.0f);
    const float Tbf      = fdescale(fsigmoid(pp[5]), -5.0f, 2.0f);
    const float SWI      = fdescale(fsigmoid(pp[7]), 0.0f, 0.4f);
    const float Tbm      = fdescale(fsigmoid(pp[8]), -2.0f, 3.0f);
    const float ddfsum   = ddf_min + ddf_plus;
    const float ddfK     = ddf_min * Kcum;

    float w0, w2_;
    {
        float r0 = pp[24], r1 = pp[25], r2 = pp[26];
        float m = fmaxf(fmaxf(r0, r1), r2);
        float e0 = fexp(r0 - m), e1 = fexp(r1 - m), e2 = fexp(r2 - m);
        float inv = 1.0f / (e0 + e1 + e2);
        w0 = e0 * inv; w2_ = e2 * inv;
    }

    float sp0 = 0.f, lw0 = 0.f, cm0 = 0.f;   // hbv
    float sp2 = 0.f, cm2 = 0.f;              // simple

    float bR[GRP], bS[GRP], bD[GRP], bX[GRP];
    float rawP[GRP], rawT[GRP];
    #pragma unroll
    for (int j = 0; j < GRP; ++j) {
        size_t a = ((size_t)j * G_CELLS + (size_t)g) * 3;
        rawP[j] = x[a]; rawT[j] = x[a + 1];
    }
    #pragma unroll
    for (int j = 0; j < GRP; ++j) {
        float tm = rawT[j], prcp = rawP[j];
        bR[j] = (tm > 0.0f) ? prcp : 0.0f;
        bS[j] = prcp - bR[j];
        bD[j] = tm - Tbm;
        bX[j] = Kf * fmaxf(Tbf - tm, NZF);
    }

    for (int k = 0; k < NITER; ++k) {
        block_barrier();
        if (k < NGRP) {
            const int kn = (k + 1 < NGRP) ? k + 1 : NGRP - 1;
            #pragma unroll
            for (int j = 0; j < GRP; ++j) {
                size_t a = ((size_t)(kn * GRP + j) * G_CELLS + (size_t)g) * 3;
                rawP[j] = x[a]; rawT[j] = x[a + 1];
            }

            const int b = k & 1;
            #pragma unroll
            for (int j = 0; j < GRP; ++j) {
                const float rain = bR[j], snow = bS[j], dtm = bD[j];
                float oA, oB;
                {   // hbv
                    float ddf  = fminf(ddfsum, fmaf(ddfK, cm0, ddf_min));
                    float pm   = fmaxf(ddf * dtm, 0.0f);
                    float rfz  = fminf(bX[j], lw0);
                    sp0 = sp0 + snow + rfz;
                    float melt = fminf(pm, sp0 + snow + rfz);   // reference quirk
                    cm0 = (sp0 > NZF) ? (cm0 + melt) : 0.0f;
                    sp0 = fmaxf(sp0 - melt, NZF);
                    float wret = SWI * sp0;
                    float wtmp = lw0 + melt + rain;
                    oA = fmaxf(wtmp - wret, 0.0f);
                    lw0 = fminf(wtmp, wret);
                }
                {   // simple
                    float ddf  = fminf(ddfsum, fmaf(ddfK, cm2, ddf_min));
                    float pm   = fmaxf(ddf * dtm, 0.0f);
                    float melt = fminf(pm, sp2);
                    sp2 = sp2 + snow - melt;
                    oB = melt + rain;
                    cm2 = (sp2 > NZF) ? (cm2 + melt) : 0.0f;
                }
                ob[b][0][j][lane] = w0 * oA + w2_ * oB;
            }

            #pragma unroll
            for (int j = 0; j < GRP; ++j) {
                float tm = rawT[j], prcp = rawP[j];
                bR[j] = (tm > 0.0f) ? prcp : 0.0f;
                bS[j] = prcp - bR[j];
                bD[j] = tm - Tbm;
                bX[j] = Kf * fmaxf(Tbf - tm, NZF);
            }
        }
    }
}

// ===================== wave 1: hmets =====================
__device__ __forceinline__ void snow1_wave(const float* __restrict__ x,
                                           const float* __restrict__ pp,
                                           float (*ob)[2][GRP][CPB],
                                           int lane, int g)
{
    const float ddf_min  = fdescale(fsigmoid(pp[0]), 0.0f, 20.0f);
    const float ddf_plus = fdescale(fsigmoid(pp[1]), 0.0f, 20.0f);
    const float Kcum     = fdescale(fsigmoid(pp[2]), 0.01f, 0.2f);
    const float Kf       = fdescale(fsigmoid(pp[3]), 0.0f, 5.0f);
    const float exp_fe   = fdescale(fsigmoid(pp[4]), 0.0f, 1.0f);
    const float Tbf      = fdescale(fsigmoid(pp[5]), -5.0f, 2.0f);
    const float Ccum     = fdescale(fsigmoid(pp[6]), 0.005f, 0.05f);
    const float Tbm      = fdescale(fsigmoid(pp[8]), -2.0f, 3.0f);
    const float fcmin    = fdescale(fsigmoid(pp[9]), 0.0f, 0.1f);
    const float fcsum    = fcmin + fdescale(fsigmoid(pp[10]), 0.01f, 0.25f);
    const float ddfsum   = ddf_min + ddf_plus;
    const float ddfK     = ddf_min * Kcum;

    float w1;
    {
        float r0 = pp[24], r1 = pp[25], r2 = pp[26];
        float m = fmaxf(fmaxf(r0, r1), r2);
        float e0 = fexp(r0 - m), e1 = fexp(r1 - m), e2 = fexp(r2 - m);
        w1 = e1 / (e0 + e1 + e2);
    }

    float sp = 0.f, lw = 0.f, cm = 0.f;

    float bR[GRP], bS[GRP], bD[GRP], bX[GRP];
    float rawP[GRP], rawT[GRP];
    #pragma unroll
    for (int j = 0; j < GRP; ++j) {
        size_t a = ((size_t)j * G_CELLS + (size_t)g) * 3;
        rawP[j] = x[a]; rawT[j] = x[a + 1];
    }
    #pragma unroll
    for (int j = 0; j < GRP; ++j) {
        float tm = rawT[j], prcp = rawP[j];
        bR[j] = (tm > 0.0f) ? prcp : 0.0f;
        bS[j] = prcp - bR[j];
        bD[j] = tm - Tbm;
        bX[j] = Kf * fpow(fmaxf(Tbf - tm, NZF), exp_fe);
    }

    for (int k = 0; k < NITER; ++k) {
        block_barrier();
        if (k < NGRP) {
            const int kn = (k + 1 < NGRP) ? k + 1 : NGRP - 1;
            #pragma unroll
            for (int j = 0; j < GRP; ++j) {
                size_t a = ((size_t)(kn * GRP + j) * G_CELLS + (size_t)g) * 3;
                rawP[j] = x[a]; rawT[j] = x[a + 1];
            }

            const int b = k & 1;
            #pragma unroll
            for (int j = 0; j < GRP; ++j) {
                const float rain = bR[j], snow = bS[j], dtm = bD[j];
                float ddf  = fminf(ddfsum, fmaf(ddfK, cm, ddf_min));
                float pm   = fmaxf(ddf * dtm, 0.0f);
                float rfz  = fminf(bX[j], lw);
                lw -= rfz; sp += rfz;
                float melt = fminf(pm, sp + snow);
                sp = sp + snow - melt;
                cm = (sp > NZF) ? (cm + melt) : 0.0f;
                float wrf  = fmaxf(fcsum * (1.0f - Ccum * cm), fcmin);
                float wret = wrf * sp;
                float wtmp = lw + melt + rain;
                float o    = fmaxf(wtmp - wret, 0.0f);
                lw = fminf(wtmp, wret);
                cm = (sp > NZF) ? (cm + melt) : 0.0f;      // reference quirk: double update
                ob[b][1][j][lane] = w1 * o;
            }

            #pragma unroll
            for (int j = 0; j < GRP; ++j) {
                float tm = rawT[j], prcp = rawP[j];
                bR[j] = (tm > 0.0f) ? prcp : 0.0f;
                bS[j] = prcp - bR[j];
                bD[j] = tm - Tbm;
                bX[j] = Kf * fpow(fmaxf(Tbf - tm, NZF), exp_fe);
            }
        }
    }
}

// ===================== wave 2: vadose chain (lag 1, HW transcendentals) =====================
__device__ __forceinline__ void vad_wave(const float* __restrict__ x,
                                         const float* __restrict__ pp,
                                         float (*ob)[2][GRP][CPB],
                                         float (*pr)[2][GRP][CPB],
                                         int lane, int g)
{
    const float vmax        = fdescale(fsigmoid(pp[11]), 0.001f, 500.0f);
    const float hmets_alpha = fdescale(fsigmoid(pp[12]), 0.0f, 1.0f);
    const float vic_beta    = fdescale(fsigmoid(pp[13]), 0.1f, 3.0f);
    const float hbv_beta    = fdescale(fsigmoid(pp[14]), 0.5f, 3.0f);
    const float quickflow_k = fdescale(fsigmoid(pp[15]), -5.0f, -2.0f);
    const float qn          = fdescale(fsigmoid(pp[16]), 0.5f, 2.0f);
    const float mmax        = fdescale(fsigmoid(pp[17]), 0.0f, 100.0f);
    const float lamb        = fdescale(fsigmoid(pp[18]), 5.0f, 10.0f);
    const float ET_eff      = fdescale(fsigmoid(pp[21]), 0.0f, 3.0f);
    const float cv2p        = fdescale(fsigmoid(pp[22]), 1e-5f, 0.02f);

    float w4, w5, w6, w7, w8, w9;
    {
        float r0 = pp[27], r1 = pp[28], r2 = pp[29];
        float m = fmaxf(fmaxf(r0, r1), r2);
        float e0 = fexp(r0 - m), e1 = fexp(r1 - m), e2 = fexp(r2 - m);
        float inv = 1.0f / (e0 + e1 + e2);
        w4 = e0 * inv; w5 = e1 * inv; w6 = e2 * inv;
    }
    {
        float r0 = pp[30], r1 = pp[31], r2 = pp[32];
        float m = fmaxf(fmaxf(r0, r1), r2);
        float e0 = fexp(r0 - m), e1 = fexp(r1 - m), e2 = fexp(r2 - m);
        float inv = 1.0f / (e0 + e1 + e2);
        w7 = e0 * inv; w8 = e1 * inv; w9 = e2 * inv;
    }

    const float inv_vmax    = 1.0f / vmax;
    const float qk10        = fexp2(quickflow_k * LOG2_10);
    const float qf_top_coef = mmax * (vmax / qn) * fexp2(-qn * flog2(lamb));
    const float w7qk        = w7 * qk10;
    const float hi_clamp    = 1.0f - NZF;
    const float l2top       = flog2(qf_top_coef);
    const float l2vic       = flog2(mmax);
    const float one_m_cv2p  = 1.0f - cv2p;
    const float k_vv        = one_m_cv2p * inv_vmax;

    float vad = 0.f;
    float VV  = 0.f;     // == vad * inv_vmax

    float petReg[GRP], petNew[GRP];
    #pragma unroll
    for (int j = 0; j < GRP; ++j)
        petReg[j] = x[((size_t)j * G_CELLS + (size_t)g) * 3 + 2];

    for (int k = 0; k < NITER; ++k) {
        block_barrier();
        if (k >= 1 && k <= NGRP) {
            const int kg = k - 1;
            const int kn = (kg + 1 < NGRP) ? kg + 1 : NGRP - 1;
            #pragma unroll
            for (int j = 0; j < GRP; ++j)
                petNew[j] = x[((size_t)(kn * GRP + j) * G_CELLS + (size_t)g) * 3 + 2];

            const int bo   = kg & 1;
            const int slot = kg & 1;
            #pragma unroll
            for (int j = 0; j < GRP; ++j) {
                const float rrj = ob[bo][0][j][lane] + ob[bo][1][j][lane];
                const float pej = petReg[j] * ET_eff;
                float om  = fmed3(1.0f - VV, NZF, hi_clamp);
                float l1  = flog2(om);
                float phbv = fexp2(hbv_beta * l1);
                float pvic = fexp2(vic_beta * l1);
                float a4 = w4 * rrj;
                float a6 = w6 * rrj;
                float base = fmaf(w5 * rrj, fmaf(-hmets_alpha, VV, 1.0f), a6);
                float inf = fmaf(a4, phbv, fmaf(-a6, pvic, base));
                inf = fmed3(inf, 0.0f, rrj);
                float surface = rrj - inf;
                float vad1 = vad + inf;
                float VV1  = fmaf(inf, inv_vmax, VV);
                float sprop1 = fmed3(VV1, NZF, hi_clamp);
                float lq = flog2(sprop1);
                float topt = fexp2(fmaf(qn, lq, l2top));
                float vict = fexp2(fmaf(qn, lq, l2vic));
                float vad2 = fmaxf(fmaf(-pej, sprop1, vad1), 0.0f);
                float qf_top = fminf(topt, vad2);
                float qf_vic = fminf(vict, vad2);
                float S  = fmaf(w7qk, vad2, fmaf(w8, qf_top, w9 * qf_vic));
                float qf = fminf(S, vad2);
                float vad3 = vad2 - qf;

                pr[slot][0][j][lane] = cv2p * vad3;
                pr[slot][1][j][lane] = surface + qf;
                vad = vad3 * one_m_cv2p;
                VV  = vad3 * k_vv;
            }

            #pragma unroll
            for (int j = 0; j < GRP; ++j) petReg[j] = petNew[j];
        }
    }
}

// ===================== wave 3: phreatic chain + fused routing (lag 2) =====================
__device__ __forceinline__ void phr_route_wave(const float* __restrict__ pp,
                                               float (*pr)[2][GRP][CPB],
                                               float* __restrict__ out,
                                               int lane, int g)
{
    const float baseflow_k = fdescale(fsigmoid(pp[19]), -5.0f, -1.0f);
    const float bn         = fdescale(fsigmoid(pp[20]), 0.5f, 2.0f);
    float w10, w11;
    {
        float r0 = pp[33], r1 = pp[34];
        float m = fmaxf(r0, r1);
        float e0 = fexp(r0 - m), e1 = fexp(r1 - m);
        float inv = 1.0f / (e0 + e1);
        w10 = e0 * inv; w11 = e1 * inv;
    }
    const float bk10 = fexp2(baseflow_k * LOG2_10);
    const float c_b1 = w10 * bk10, c_b2 = w11 * bk10;

    const float a1 = fdescale(fsigmoid(pp[35]), 0.3f, 20.0f);
    const float b1 = fdescale(fsigmoid(pp[36]), 0.01f, 5.0f);
    const float a2 = fdescale(fsigmoid(pp[37]), 0.5f, 13.0f);
    const float b2 = fdescale(fsigmoid(pp[38]), 0.15f, 1.5f);

    const float LOG2T[L_UHN] = {
        -1.0f, 0.58496250072116f, 1.32192809488736f, 1.80735492205760f,
        2.16992500144231f, 2.45943161863730f, 2.70043971814109f,
        2.90689059560852f, 3.08746284125034f, 3.24792751344359f,
        3.39231742277876f, 3.52356195605701f, 3.64385618977472f,
        3.75488750216347f, 3.85798099512757f };

    float uh1[L_UHN], uh2[L_UHN];
    {
        float rb1 = LOG2E / b1, rb2 = LOG2E / b2;
        float s1 = 0.0f, s2 = 0.0f;
        #pragma unroll
        for (int kk = 0; kk < L_UHN; ++kk) {
            float tk = (float)kk + 0.5f;
            float v1 = fexp2((a1 - 1.0f) * LOG2T[kk] - tk * rb1);
            float v2 = fexp2((a2 - 1.0f) * LOG2T[kk] - tk * rb2);
            uh1[kk] = v1; uh2[kk] = v2; s1 += v1; s2 += v2;
        }
        float i1 = 1.0f / s1, i2 = 1.0f / s2;
        #pragma unroll
        for (int kk = 0; kk < L_UHN; ++kk) { uh1[kk] *= i1; uh2[kk] *= i2; }
    }

    float phr = 0.f;
    float fut[L_UHN];
    #pragma unroll
    for (int kk = 0; kk < L_UHN; ++kk) fut[kk] = 0.0f;

    for (int k = 0; k < NITER; ++k) {
        block_barrier();
        if (k >= 2) {
            const int kg = k - 2;
            const int slot = kg & 1;
            #pragma unroll
            for (int j = 0; j < GRP; ++j) {
                float pc = pr[slot][0][j][lane];
                float qt = pr[slot][1][j][lane];
                phr += pc;
                float pb = fexp2(bn * flog2(fmaxf(phr, NZF)));
                float bf = fminf(fmaf(c_b1, phr, c_b2 * pb), phr);
                phr -= bf;

                #pragma unroll
                for (int kk = 0; kk < L_UHN; ++kk)
                    fut[kk] = fmaf(uh1[kk], qt, fmaf(uh2[kk], bf, fut[kk]));
                out[(size_t)(kg * GRP + j) * G_CELLS + (size_t)g] = fut[0];
                #pragma unroll
                for (int kk = 0; kk < L_UHN - 1; ++kk) fut[kk] = fut[kk + 1];
                fut[L_UHN - 1] = 0.0f;
            }
        }
    }
}

__global__ __launch_bounds__(256, 1) void pipeline_kernel(
    const float* __restrict__ x, const float* __restrict__ params,
    float* __restrict__ out)
{
    __shared__ float ob[2][2][GRP][CPB];    // 32 KB  [buf][0=hbv+simple,1=hmets]
    __shared__ float pr[2][2][GRP][CPB];    // 32 KB  [slot][0=perc,1=quick]
    const int lane = threadIdx.x & 63;
    const int wave = threadIdx.x >> 6;
    const int g    = blockIdx.x * CPB + lane;
    const float* pp = params + ((size_t)(T_STEPS - 1) * G_CELLS + (size_t)g) * 39;

    if (wave == 0)      snow02_wave(x, pp, ob, lane, g);
    else if (wave == 1) snow1_wave(x, pp, ob, lane, g);
    else if (wave == 2) vad_wave(x, pp, ob, pr, lane, g);
    else                phr_route_wave(pp, pr, out, lane, g);
}

extern "C" void kernel_launch(void* const* d_in, const int* in_sizes, int n_in,
                              void* d_out, int out_size, void* d_ws, size_t ws_size,
                              hipStream_t stream) {
    const float* x      = (const float*)d_in[0];
    const float* params = (const float*)d_in[1];
    float* out          = (float*)d_out;
    pipeline_kernel<<<dim3(G_CELLS / CPB), dim3(256), 0, stream>>>(x, params, out);
}

// Round 19
// 68.783 us; speedup vs baseline: 1.4353x; 1.0375x over previous
//
#include <hip/hip_runtime.h>

#define T_STEPS 512
#define G_CELLS 4096
#define L_UHN   15
#define GRP     16
#define NGRP    (T_STEPS / GRP)   // 32
#define NITER   (NGRP + 2)        // 34: snow@k, vad@k-1, route@k-2
#define CPB     64                // cells per block (one lane each)
#define NZF     1e-5f
#define LOG2E   1.44269504088896340736f
#define LOG2_10 3.32192809488736234787f

__device__ __forceinline__ float fexp2(float x) { return __builtin_amdgcn_exp2f(x); }
__device__ __forceinline__ float flog2(float x) { return __builtin_amdgcn_logf(x); }
__device__ __forceinline__ float fmed3(float x, float lo, float hi) { return __builtin_amdgcn_fmed3f(x, lo, hi); }
__device__ __forceinline__ float fpow(float a, float b) { return fexp2(b * flog2(a)); }
__device__ __forceinline__ float fexp(float x) { return fexp2(x * LOG2E); }
__device__ __forceinline__ float fsigmoid(float v) { return 1.0f / (1.0f + fexp(-v)); }
__device__ __forceinline__ float fdescale(float s, float lo, float hi) { return lo + s * (hi - lo); }

__device__ __forceinline__ void block_barrier() {
    asm volatile("s_waitcnt lgkmcnt(0)" ::: "memory");
    __builtin_amdgcn_s_barrier();
}

// Pipeline (one barrier per iteration k, k = 0..NITER-1):
//   snow02 / hmets : group k    -> ob[k&1]
//   vad            : group k-1  (reads ob[(k-1)&1] directly) -> pr[(k-1)&1]
//   phr+route      : group k-2  (reads pr[(k-2)&1] directly) -> out

// ===================== wave 0: hbv + simple (combined slot) =====================
__device__ __forceinline__ void snow02_wave(const float* __restrict__ x,
                                            const float* __restrict__ pp,
                                            float (*ob)[2][GRP][CPB],
                                            int lane, int g)
{
    const float ddf_min  = fdescale(fsigmoid(pp[0]), 0.0f, 20.0f);
    const float ddf_plus = fdescale(fsigmoid(pp[1]), 0.0f, 20.0f);
    const float Kcum     = fdescale(fsigmoid(pp[2]), 0.01f, 0.2f);
    const float Kf       = fdescale(fsigmoid(pp[3]), 0.0f, 5.0f);
    const float Tbf      = fdescale(fsigmoid(pp[5]), -5.0f, 2.0f);
    const float SWI      = fdescale(fsigmoid(pp[7]), 0.0f, 0.4f);
    const float Tbm      = fdescale(fsigmoid(pp[8]), -2.0f, 3.0f);
    const float ddfsum   = ddf_min + ddf_plus;
    const float ddfK     = ddf_min * Kcum;

    float w0, w2_;
    {
        float r0 = pp[24], r1 = pp[25], r2 = pp[26];
        float m = fmaxf(fmaxf(r0, r1), r2);
        float e0 = fexp(r0 - m), e1 = fexp(r1 - m), e2 = fexp(r2 - m);
        float inv = 1.0f / (e0 + e1 + e2);
        w0 = e0 * inv; w2_ = e2 * inv;
    }

    float sp0 = 0.f, lw0 = 0.f, cm0 = 0.f;   // hbv
    float sp2 = 0.f, cm2 = 0.f;              // simple

    float bR[GRP], bS[GRP], bD[GRP], bX[GRP];
    float rawP[GRP], rawT[GRP];
    #pragma unroll
    for (int j = 0; j < GRP; ++j) {
        size_t a = ((size_t)j * G_CELLS + (size_t)g) * 3;
        rawP[j] = x[a]; rawT[j] = x[a + 1];
    }
    #pragma unroll
    for (int j = 0; j < GRP; ++j) {
        float tm = rawT[j], prcp = rawP[j];
        bR[j] = (tm > 0.0f) ? prcp : 0.0f;
        bS[j] = prcp - bR[j];
        bD[j] = tm - Tbm;
        bX[j] = Kf * fmaxf(Tbf - tm, NZF);
    }

    for (int k = 0; k < NITER; ++k) {
        block_barrier();
        if (k < NGRP) {
            const int kn = (k + 1 < NGRP) ? k + 1 : NGRP - 1;
            #pragma unroll
            for (int j = 0; j < GRP; ++j) {
                size_t a = ((size_t)(kn * GRP + j) * G_CELLS + (size_t)g) * 3;
                rawP[j] = x[a]; rawT[j] = x[a + 1];
            }

            const int b = k & 1;
            #pragma unroll
            for (int j = 0; j < GRP; ++j) {
                const float rain = bR[j], snow = bS[j], dtm = bD[j];
                float oA, oB;
                {   // hbv
                    float ddf  = fminf(ddfsum, fmaf(ddfK, cm0, ddf_min));
                    float pm   = fmaxf(ddf * dtm, 0.0f);
                    float rfz  = fminf(bX[j], lw0);
                    sp0 = sp0 + snow + rfz;
                    float melt = fminf(pm, sp0 + snow + rfz);   // reference quirk
                    cm0 = (sp0 > NZF) ? (cm0 + melt) : 0.0f;
                    sp0 = fmaxf(sp0 - melt, NZF);
                    float wret = SWI * sp0;
                    float wtmp = lw0 + melt + rain;
                    oA = fmaxf(wtmp - wret, 0.0f);
                    lw0 = fminf(wtmp, wret);
                }
                {   // simple
                    float ddf  = fminf(ddfsum, fmaf(ddfK, cm2, ddf_min));
                    float pm   = fmaxf(ddf * dtm, 0.0f);
                    float melt = fminf(pm, sp2);
                    sp2 = sp2 + snow - melt;
                    oB = melt + rain;
                    cm2 = (sp2 > NZF) ? (cm2 + melt) : 0.0f;
                }
                ob[b][0][j][lane] = w0 * oA + w2_ * oB;
            }

            #pragma unroll
            for (int j = 0; j < GRP; ++j) {
                float tm = rawT[j], prcp = rawP[j];
                bR[j] = (tm > 0.0f) ? prcp : 0.0f;
                bS[j] = prcp - bR[j];
                bD[j] = tm - Tbm;
                bX[j] = Kf * fmaxf(Tbf - tm, NZF);
            }
        }
    }
}

// ===================== wave 1: hmets =====================
__device__ __forceinline__ void snow1_wave(const float* __restrict__ x,
                                           const float* __restrict__ pp,
                                           float (*ob)[2][GRP][CPB],
                                           int lane, int g)
{
    const float ddf_min  = fdescale(fsigmoid(pp[0]), 0.0f, 20.0f);
    const float ddf_plus = fdescale(fsigmoid(pp[1]), 0.0f, 20.0f);
    const float Kcum     = fdescale(fsigmoid(pp[2]), 0.01f, 0.2f);
    const float Kf       = fdescale(fsigmoid(pp[3]), 0.0f, 5.0f);
    const float exp_fe   = fdescale(fsigmoid(pp[4]), 0.0f, 1.0f);
    const float Tbf      = fdescale(fsigmoid(pp[5]), -5.0f, 2.0f);
    const float Ccum     = fdescale(fsigmoid(pp[6]), 0.005f, 0.05f);
    const float Tbm      = fdescale(fsigmoid(pp[8]), -2.0f, 3.0f);
    const float fcmin    = fdescale(fsigmoid(pp[9]), 0.0f, 0.1f);
    const float fcsum    = fcmin + fdescale(fsigmoid(pp[10]), 0.01f, 0.25f);
    const float ddfsum   = ddf_min + ddf_plus;
    const float ddfK     = ddf_min * Kcum;

    float w1;
    {
        float r0 = pp[24], r1 = pp[25], r2 = pp[26];
        float m = fmaxf(fmaxf(r0, r1), r2);
        float e0 = fexp(r0 - m), e1 = fexp(r1 - m), e2 = fexp(r2 - m);
        w1 = e1 / (e0 + e1 + e2);
    }

    float sp = 0.f, lw = 0.f, cm = 0.f;

    float bR[GRP], bS[GRP], bD[GRP], bX[GRP];
    float rawP[GRP], rawT[GRP];
    #pragma unroll
    for (int j = 0; j < GRP; ++j) {
        size_t a = ((size_t)j * G_CELLS + (size_t)g) * 3;
        rawP[j] = x[a]; rawT[j] = x[a + 1];
    }
    #pragma unroll
    for (int j = 0; j < GRP; ++j) {
        float tm = rawT[j], prcp = rawP[j];
        bR[j] = (tm > 0.0f) ? prcp : 0.0f;
        bS[j] = prcp - bR[j];
        bD[j] = tm - Tbm;
        bX[j] = Kf * fpow(fmaxf(Tbf - tm, NZF), exp_fe);
    }

    for (int k = 0; k < NITER; ++k) {
        block_barrier();
        if (k < NGRP) {
            const int kn = (k + 1 < NGRP) ? k + 1 : NGRP - 1;
            #pragma unroll
            for (int j = 0; j < GRP; ++j) {
                size_t a = ((size_t)(kn * GRP + j) * G_CELLS + (size_t)g) * 3;
                rawP[j] = x[a]; rawT[j] = x[a + 1];
            }

            const int b = k & 1;
            #pragma unroll
            for (int j = 0; j < GRP; ++j) {
                const float rain = bR[j], snow = bS[j], dtm = bD[j];
                float ddf  = fminf(ddfsum, fmaf(ddfK, cm, ddf_min));
                float pm   = fmaxf(ddf * dtm, 0.0f);
                float rfz  = fminf(bX[j], lw);
                lw -= rfz; sp += rfz;
                float melt = fminf(pm, sp + snow);
                sp = sp + snow - melt;
                cm = (sp > NZF) ? (cm + melt) : 0.0f;
                float wrf  = fmaxf(fcsum * (1.0f - Ccum * cm), fcmin);
                float wret = wrf * sp;
                float wtmp = lw + melt + rain;
                float o    = fmaxf(wtmp - wret, 0.0f);
                lw = fminf(wtmp, wret);
                cm = (sp > NZF) ? (cm + melt) : 0.0f;      // reference quirk: double update
                ob[b][1][j][lane] = w1 * o;
            }

            #pragma unroll
            for (int j = 0; j < GRP; ++j) {
                float tm = rawT[j], prcp = rawP[j];
                bR[j] = (tm > 0.0f) ? prcp : 0.0f;
                bS[j] = prcp - bR[j];
                bD[j] = tm - Tbm;
                bX[j] = Kf * fpow(fmaxf(Tbf - tm, NZF), exp_fe);
            }
        }
    }
}

// ===================== wave 2: vadose chain (lag 1, HW transcendentals) =====================
__device__ __forceinline__ void vad_wave(const float* __restrict__ x,
                                         const float* __restrict__ pp,
                                         float (*ob)[2][GRP][CPB],
                                         float (*pr)[2][GRP][CPB],
                                         int lane, int g)
{
    const float vmax        = fdescale(fsigmoid(pp[11]), 0.001f, 500.0f);
    const float hmets_alpha = fdescale(fsigmoid(pp[12]), 0.0f, 1.0f);
    const float vic_beta    = fdescale(fsigmoid(pp[13]), 0.1f, 3.0f);
    const float hbv_beta    = fdescale(fsigmoid(pp[14]), 0.5f, 3.0f);
    const float quickflow_k = fdescale(fsigmoid(pp[15]), -5.0f, -2.0f);
    const float qn          = fdescale(fsigmoid(pp[16]), 0.5f, 2.0f);
    const float mmax        = fdescale(fsigmoid(pp[17]), 0.0f, 100.0f);
    const float lamb        = fdescale(fsigmoid(pp[18]), 5.0f, 10.0f);
    const float ET_eff      = fdescale(fsigmoid(pp[21]), 0.0f, 3.0f);
    const float cv2p        = fdescale(fsigmoid(pp[22]), 1e-5f, 0.02f);

    float w4, w5, w6, w7, w8, w9;
    {
        float r0 = pp[27], r1 = pp[28], r2 = pp[29];
        float m = fmaxf(fmaxf(r0, r1), r2);
        float e0 = fexp(r0 - m), e1 = fexp(r1 - m), e2 = fexp(r2 - m);
        float inv = 1.0f / (e0 + e1 + e2);
        w4 = e0 * inv; w5 = e1 * inv; w6 = e2 * inv;
    }
    {
        float r0 = pp[30], r1 = pp[31], r2 = pp[32];
        float m = fmaxf(fmaxf(r0, r1), r2);
        float e0 = fexp(r0 - m), e1 = fexp(r1 - m), e2 = fexp(r2 - m);
        float inv = 1.0f / (e0 + e1 + e2);
        w7 = e0 * inv; w8 = e1 * inv; w9 = e2 * inv;
    }

    const float inv_vmax    = 1.0f / vmax;
    const float qk10        = fexp2(quickflow_k * LOG2_10);
    const float qf_top_coef = mmax * (vmax / qn) * fexp2(-qn * flog2(lamb));
    const float w7qk        = w7 * qk10;
    const float hi_clamp    = 1.0f - NZF;
    const float l2top       = flog2(qf_top_coef);
    const float l2vic       = flog2(mmax);
    const float one_m_cv2p  = 1.0f - cv2p;
    const float k_vv        = one_m_cv2p * inv_vmax;

    float vad = 0.f;
    float VV  = 0.f;     // == vad * inv_vmax

    float petReg[GRP], petNew[GRP];
    #pragma unroll
    for (int j = 0; j < GRP; ++j)
        petReg[j] = x[((size_t)j * G_CELLS + (size_t)g) * 3 + 2];

    for (int k = 0; k < NITER; ++k) {
        block_barrier();
        if (k >= 1 && k <= NGRP) {
            const int kg = k - 1;
            const int kn = (kg + 1 < NGRP) ? kg + 1 : NGRP - 1;
            #pragma unroll
            for (int j = 0; j < GRP; ++j)
                petNew[j] = x[((size_t)(kn * GRP + j) * G_CELLS + (size_t)g) * 3 + 2];

            const int bo   = kg & 1;
            const int slot = kg & 1;
            #pragma unroll
            for (int j = 0; j < GRP; ++j) {
                const float rrj = ob[bo][0][j][lane] + ob[bo][1][j][lane];
                const float pej = petReg[j] * ET_eff;
                float om  = fmed3(1.0f - VV, NZF, hi_clamp);
                float l1  = flog2(om);
                float phbv = fexp2(hbv_beta * l1);
                float pvic = fexp2(vic_beta * l1);
                float a4 = w4 * rrj;
                float a6 = w6 * rrj;
                float base = fmaf(w5 * rrj, fmaf(-hmets_alpha, VV, 1.0f), a6);
                float inf = fmaf(a4, phbv, fmaf(-a6, pvic, base));
                inf = fmed3(inf, 0.0f, rrj);
                float surface = rrj - inf;
                float vad1 = vad + inf;
                float VV1  = fmaf(inf, inv_vmax, VV);
                float sprop1 = fmed3(VV1, NZF, hi_clamp);
                float lq = flog2(sprop1);
                float topt = fexp2(fmaf(qn, lq, l2top));
                float vict = fexp2(fmaf(qn, lq, l2vic));
                float vad2 = fmaxf(fmaf(-pej, sprop1, vad1), 0.0f);
                float qf_top = fminf(topt, vad2);
                float qf_vic = fminf(vict, vad2);
                float S  = fmaf(w7qk, vad2, fmaf(w8, qf_top, w9 * qf_vic));
                float qf = fminf(S, vad2);
                float vad3 = vad2 - qf;

                pr[slot][0][j][lane] = cv2p * vad3;
                pr[slot][1][j][lane] = surface + qf;
                vad = vad3 * one_m_cv2p;
                VV  = vad3 * k_vv;
            }

            #pragma unroll
            for (int j = 0; j < GRP; ++j) petReg[j] = petNew[j];
        }
    }
}

// ===================== wave 3: phreatic chain + fused routing (lag 2) =====================
__device__ __forceinline__ void phr_route_wave(const float* __restrict__ pp,
                                               float (*pr)[2][GRP][CPB],
                                               float* __restrict__ out,
                                               int lane, int g)
{
    const float baseflow_k = fdescale(fsigmoid(pp[19]), -5.0f, -1.0f);
    const float bn         = fdescale(fsigmoid(pp[20]), 0.5f, 2.0f);
    float w10, w11;
    {
        float r0 = pp[33], r1 = pp[34];
        float m = fmaxf(r0, r1);
        float e0 = fexp(r0 - m), e1 = fexp(r1 - m);
        float inv = 1.0f / (e0 + e1);
        w10 = e0 * inv; w11 = e1 * inv;
    }
    const float bk10 = fexp2(baseflow_k * LOG2_10);
    const float c_b1 = w10 * bk10, c_b2 = w11 * bk10;

    const float a1 = fdescale(fsigmoid(pp[35]), 0.3f, 20.0f);
    const float b1 = fdescale(fsigmoid(pp[36]), 0.01f, 5.0f);
    const float a2 = fdescale(fsigmoid(pp[37]), 0.5f, 13.0f);
    const float b2 = fdescale(fsigmoid(pp[38]), 0.15f, 1.5f);

    const float LOG2T[L_UHN] = {
        -1.0f, 0.58496250072116f, 1.32192809488736f, 1.80735492205760f,
        2.16992500144231f, 2.45943161863730f, 2.70043971814109f,
        2.90689059560852f, 3.08746284125034f, 3.24792751344359f,
        3.39231742277876f, 3.52356195605701f, 3.64385618977472f,
        3.75488750216347f, 3.85798099512757f };

    float uh1[L_UHN], uh2[L_UHN];
    {
        float rb1 = LOG2E / b1, rb2 = LOG2E / b2;
        float s1 = 0.0f, s2 = 0.0f;
        #pragma unroll
        for (int kk = 0; kk < L_UHN; ++kk) {
            float tk = (float)kk + 0.5f;
            float v1 = fexp2((a1 - 1.0f) * LOG2T[kk] - tk * rb1);
            float v2 = fexp2((a2 - 1.0f) * LOG2T[kk] - tk * rb2);
            uh1[kk] = v1; uh2[kk] = v2; s1 += v1; s2 += v2;
        }
        float i1 = 1.0f / s1, i2 = 1.0f / s2;
        #pragma unroll
        for (int kk = 0; kk < L_UHN; ++kk) { uh1[kk] *= i1; uh2[kk] *= i2; }
    }

    float phr = 0.f;
    float fut[L_UHN];
    #pragma unroll
    for (int kk = 0; kk < L_UHN; ++kk) fut[kk] = 0.0f;

    for (int k = 0; k < NITER; ++k) {
        block_barrier();
        if (k >= 2) {
            const int kg = k - 2;
            const int slot = kg & 1;
            #pragma unroll
            for (int j = 0; j < GRP; ++j) {
                float pc = pr[slot][0][j][lane];
                float qt = pr[slot][1][j][lane];
                phr += pc;
                float pb = fexp2(bn * flog2(fmaxf(phr, NZF)));
                float bf = fminf(fmaf(c_b1, phr, c_b2 * pb), phr);
                phr -= bf;

                #pragma unroll
                for (int kk = 0; kk < L_UHN; ++kk)
                    fut[kk] = fmaf(uh1[kk], qt, fmaf(uh2[kk], bf, fut[kk]));
                out[(size_t)(kg * GRP + j) * G_CELLS + (size_t)g] = fut[0];
                #pragma unroll
                for (int kk = 0; kk < L_UHN - 1; ++kk) fut[kk] = fut[kk + 1];
                fut[L_UHN - 1] = 0.0f;
            }
        }
    }
}

__global__ __launch_bounds__(256, 1) void pipeline_kernel(
    const float* __restrict__ x, const float* __restrict__ params,
    float* __restrict__ out)
{
    __shared__ float ob[2][2][GRP][CPB];    // 16 KB  [buf][0=hbv+simple,1=hmets]
    __shared__ float pr[2][2][GRP][CPB];    // 16 KB  [slot][0=perc,1=quick]
    const int lane = threadIdx.x & 63;
    const int wave = threadIdx.x >> 6;
    const int g    = blockIdx.x * CPB + lane;
    const float* pp = params + ((size_t)(T_STEPS - 1) * G_CELLS + (size_t)g) * 39;

    if (wave == 0)      snow02_wave(x, pp, ob, lane, g);
    else if (wave == 1) snow1_wave(x, pp, ob, lane, g);
    else if (wave == 2) vad_wave(x, pp, ob, pr, lane, g);
    else                phr_route_wave(pp, pr, out, lane, g);
}

extern "C" void kernel_launch(void* const* d_in, const int* in_sizes, int n_in,
                              void* d_out, int out_size, void* d_ws, size_t ws_size,
                              hipStream_t stream) {
    const float* x      = (const float*)d_in[0];
    const float* params = (const float*)d_in[1];
    float* out          = (float*)d_out;
    pipeline_kernel<<<dim3(G_CELLS / CPB), dim3(256), 0, stream>>>(x, params, out);
}